// Round 3
// baseline (5053.645 us; speedup 1.0000x reference)
//
#include <hip/hip_runtime.h>
#include <stdint.h>

#define B_ 64
#define T_ 1024
#define E_ 256
#define H_ 512
#define BH_ (B_*H_)          // 32768
#define DEC_ELEMS ((size_t)B_*512*1024)

typedef __attribute__((ext_vector_type(8))) short bf16x8;
typedef __attribute__((ext_vector_type(4))) float f32x4;
typedef unsigned long long u64;

__device__ __forceinline__ unsigned short f2bf(float f) {
  union { float f; unsigned int u; } v; v.f = f;
  unsigned int r = (v.u + 0x7fffu + ((v.u >> 16) & 1u)) >> 16;
  return (unsigned short)r;
}
__device__ __forceinline__ float bf2f(unsigned short s) {
  union { float f; unsigned int u; } v; v.u = ((unsigned int)s) << 16;
  return v.f;
}
__device__ __forceinline__ float sigf(float x) { return 1.f/(1.f + __expf(-x)); }
__device__ __forceinline__ float tanhfast(float x) {
  float e = __expf(2.f*x);
  return 1.f - 2.f/(e + 1.f);
}
__device__ __forceinline__ void st4bf(unsigned short* p, float4 v) {
  ushort4 u; u.x=f2bf(v.x); u.y=f2bf(v.y); u.z=f2bf(v.z); u.w=f2bf(v.w);
  *(ushort4*)p = u;
}
// device-coherent (IF$-level) accesses, NO cache-wide maintenance ops
__device__ __forceinline__ u64 ld_dc64(const unsigned short* p) {
  return __hip_atomic_load((const u64*)p, __ATOMIC_RELAXED, __HIP_MEMORY_SCOPE_AGENT);
}
__device__ __forceinline__ void st_dc64(unsigned short* p, u64 v) {
  __hip_atomic_store((u64*)p, v, __ATOMIC_RELAXED, __HIP_MEMORY_SCOPE_AGENT);
}
__device__ __forceinline__ void st_dc32(unsigned short* p, unsigned int v) {
  __hip_atomic_store((unsigned int*)p, v, __ATOMIC_RELAXED, __HIP_MEMORY_SCOPE_AGENT);
}

// Wait until all 64 per-block flags (monotonic timestep counters) reach
// target. Polled by one wave (wv); other waves park at the barrier.
__device__ __forceinline__ void waitflags(const int* f, int target, int wv) {
  if ((threadIdx.x >> 6) == wv) {
    const int* p = f + (threadIdx.x & 63);
    for (;;) {
      int v = __hip_atomic_load(p, __ATOMIC_RELAXED, __HIP_MEMORY_SCOPE_AGENT);
      if (__all(v >= target)) break;
      __builtin_amdgcn_s_sleep(1);
    }
  }
  __syncthreads();
}

// ---------------- prep: bf16 weight copies + initial h broadcast publish ----
__global__ void k_prep(const float* __restrict__ Wenc, const float* __restrict__ Wlin,
                       const float* __restrict__ Wdec, const float* __restrict__ states,
                       unsigned short* __restrict__ wencb, unsigned short* __restrict__ wlinb,
                       unsigned short* __restrict__ wdecb,
                       unsigned short* h1bc, unsigned short* h2bc) {
  int i = blockIdx.x*256 + threadIdx.x;      // 131072 total
  if (i < 131072) {
    wencb[i] = f2bf(Wenc[i]);
    wlinb[i] = f2bf(Wlin[i]);
    wdecb[i] = f2bf(Wdec[i]);
  }
  if (i < BH_/4) {  // publish h1(-1), h2(-1) into parity-1 buffers
    float4 a  = *(const float4*)(states + (size_t)i*4);
    float4 b2 = *(const float4*)(states + (size_t)2*BH_ + (size_t)i*4);
    ushort4 ua; ua.x=f2bf(a.x);  ua.y=f2bf(a.y);  ua.z=f2bf(a.z);  ua.w=f2bf(a.w);
    ushort4 ub; ub.x=f2bf(b2.x); ub.y=f2bf(b2.y); ub.z=f2bf(b2.z); ub.w=f2bf(b2.w);
    st_dc64(&h1bc[BH_ + i*4], *(const u64*)&ua);
    st_dc64(&h2bc[BH_ + i*4], *(const u64*)&ub);
  }
}

// ---------------- encoder GEMM + LayerNorm -> enc_norm(bf16), encoded(bf16) --
__global__ __launch_bounds__(256) void k_enc(const float* __restrict__ x,
    const unsigned short* __restrict__ wencb, const float* __restrict__ lng,
    const float* __restrict__ lnb,
    unsigned short* __restrict__ enc_norm, unsigned short* __restrict__ encoded) {
  __shared__ __align__(16) unsigned short xs[16][520];
  __shared__ __align__(16) float es[16][265];
  const int bx = blockIdx.x;
  const int b = bx >> 6, tt = (bx & 63) << 4;
  const int tid = threadIdx.x;

  const float* xb = x + (size_t)b*512*1024 + tt;
  #pragma unroll
  for (int it = 0; it < 8; ++it) {
    int idx = tid + it*256;
    int c = idx >> 2, i4 = idx & 3;
    float4 v = *(const float4*)(xb + (size_t)c*1024 + i4*4);
    xs[i4*4+0][c]=f2bf(v.x); xs[i4*4+1][c]=f2bf(v.y);
    xs[i4*4+2][c]=f2bf(v.z); xs[i4*4+3][c]=f2bf(v.w);
  }
  __syncthreads();

  const int w = tid >> 6, lane = tid & 63;
  const int n16 = lane & 15, q = lane >> 4;
  f32x4 acc[4];
  #pragma unroll
  for (int i = 0; i < 4; ++i) acc[i] = (f32x4){0.f,0.f,0.f,0.f};
  for (int ks = 0; ks < 16; ++ks) {
    int k0 = ks*32 + q*8;
    bf16x8 af = *(const bf16x8*)&xs[n16][k0];
    #pragma unroll
    for (int i = 0; i < 4; ++i) {
      int o = (w*4+i)*16 + n16;
      bf16x8 bf = *(const bf16x8*)&wencb[(size_t)o*512 + k0];
      acc[i] = __builtin_amdgcn_mfma_f32_16x16x32_bf16(af, bf, acc[i], 0,0,0);
    }
  }
  #pragma unroll
  for (int i = 0; i < 4; ++i) {
    int o = (w*4+i)*16 + n16;
    #pragma unroll
    for (int r = 0; r < 4; ++r) es[q*4+r][o] = acc[i][r];
  }
  __syncthreads();

  const int tl = tid >> 4, l16 = tid & 15;
  float s = 0.f, ss = 0.f;
  #pragma unroll
  for (int k = 0; k < 16; ++k) { float v = es[tl][l16 + 16*k]; s += v; ss += v*v; }
  #pragma unroll
  for (int d = 1; d < 16; d <<= 1) { s += __shfl_xor(s, d, 64); ss += __shfl_xor(ss, d, 64); }
  float mu  = s  * (1.f/256.f);
  float var = ss * (1.f/256.f) - mu*mu;
  float rstd = rsqrtf(var + 1e-5f);
  #pragma unroll
  for (int k = 0; k < 16; ++k) {
    int o = l16 + 16*k;
    xs[tl][o] = f2bf((es[tl][o] - mu)*rstd*lng[o] + lnb[o]);
  }
  __syncthreads();
  #pragma unroll
  for (int it = 0; it < 2; ++it) {
    int idx = tid + it*256; int row = idx >> 5, ch = idx & 31;
    *(uint4*)&enc_norm[((size_t)(b*1024 + tt + row))*256 + ch*8] = *(const uint4*)&xs[row][ch*8];
  }
  __syncthreads();
  #pragma unroll
  for (int k = 0; k < 16; ++k) { int o = l16 + 16*k; xs[tl][o] = f2bf(es[tl][o]); }
  __syncthreads();
  #pragma unroll
  for (int it = 0; it < 2; ++it) {
    int idx = tid + it*256; int row = idx >> 5, ch = idx & 31;
    *(uint4*)&encoded[((size_t)(b*1024 + tt + row))*256 + ch*8] = *(const uint4*)&xs[row][ch*8];
  }
}

// ---------------- persistent 2-layer LSTM recurrence (lagged L2, wave-spec) --
// Iter t computes h1(t) and h2(t-1). Wave-specialized phases:
//  W:  waitflags f1>=t (wave1 polls); all stage h1(t-1); waves2-3 poll f2
//      while their h1 loads are in flight.
//  A:  waves0-1: L1 MFMA (full K=768, two chains kh summed -> gbuf1)
//      waves2-3: stage h2(t-2) (IF$ latency hidden under L1)
//  B:  wave0: EW1 + publish h1(t) + f1=t+1
//      waves1-2: L2 MFMA -> gbuf2;  wave3: stage enc(t+1)
//  C:  wave0: EW2 + publish h2(t-1)/x2 + f2=t; others run into next W.
// Cell state + biases live in wave0 registers. Numerics identical to the
// ps[0]+ps[1]+bias order of the previous version.
__global__ __launch_bounds__(256, 1) void k_recur(
    const float* __restrict__ states,
    const float* __restrict__ Wih1, const float* __restrict__ Whh1,
    const float* __restrict__ bih1, const float* __restrict__ bhh1,
    const float* __restrict__ Wih2, const float* __restrict__ Whh2,
    const float* __restrict__ bih2, const float* __restrict__ bhh2,
    const unsigned short* __restrict__ enc_norm,
    unsigned short* __restrict__ x2,
    unsigned short* h1bc, unsigned short* h2bc,                  // [2][B][H] bf16
    int* flags1, int* flags2,                                    // [4][64]
    float* __restrict__ out_states)                              // [4][B][H]
{
  __shared__ __align__(16) unsigned short wl1[32][776];   // [Wih1|Whh1] K=768
  __shared__ __align__(16) unsigned short wl2[32][1032];  // [Wih2|Whh2] K=1024
  __shared__ __align__(16) unsigned short inA[16][1288];  // [enc|h1|h2]
  __shared__ float gbuf1[32][17];                         // L1 gates
  __shared__ float gbuf2[32][17];                         // L2 gates

  const int tid = threadIdx.x;
  const int g  = blockIdx.x & 3;
  const int j  = blockIdx.x >> 2;
  const int b0 = g*16;
  const int hc0 = j*8;
  int* f1 = flags1 + g*64;
  int* f2 = flags2 + g*64;

  // --- load weight slices to LDS (fp32 -> bf16) ---
  for (int idx = tid; idx < 32*192; idx += 256) {
    int n = idx / 192, p = idx % 192;
    int R = (n>>3)*512 + hc0 + (n&7);
    if (p < 64) {
      st4bf(&wl1[n][p*4], *(const float4*)(Wih1 + (size_t)R*256 + p*4));
    } else {
      int p2 = p - 64;
      st4bf(&wl1[n][256 + p2*4], *(const float4*)(Whh1 + (size_t)R*512 + p2*4));
    }
  }
  for (int idx = tid; idx < 32*256; idx += 256) {
    int n = idx >> 8, p = idx & 255;
    int R = (n>>3)*512 + hc0 + (n&7);
    if (p < 128) {
      st4bf(&wl2[n][p*4], *(const float4*)(Wih2 + (size_t)R*512 + p*4));
    } else {
      int p2 = p - 128;
      st4bf(&wl2[n][512 + p2*4], *(const float4*)(Whh2 + (size_t)R*512 + p2*4));
    }
  }

  const int w = tid >> 6, lane = tid & 63;
  const int n16 = lane & 15, q = lane >> 4;

  // wave0 EW register state: cell c and biases for 2 hc per lane
  const int bE = lane & 15;      // batch row
  const int hp = lane >> 4;      // hc pair index 0..3 -> hc = 2*hp, 2*hp+1
  float cb1[2], cb2[2], b1r[4][2], b2r[4][2];
  if (w == 0) {
    #pragma unroll
    for (int e = 0; e < 2; ++e) {
      int col = hc0 + 2*hp + e;
      cb1[e] = states[(size_t)1*BH_ + (b0+bE)*H_ + col];
      cb2[e] = states[(size_t)3*BH_ + (b0+bE)*H_ + col];
      #pragma unroll
      for (int gi = 0; gi < 4; ++gi) {
        int R = gi*512 + col;
        b1r[gi][e] = bih1[R] + bhh1[R];
        b2r[gi][e] = bih2[R] + bhh2[R];
      }
    }
  }

  // prologue: stage enc(0) (bar A of t=0 orders it before L1 reads)
  #pragma unroll
  for (int it = 0; it < 2; ++it) {
    int idx = tid + it*256;
    int b = idx >> 5, p = idx & 31;
    *(uint4*)&inA[b][p*8] = *(const uint4*)&enc_norm[((size_t)(b0+b)*T_ + 0)*E_ + p*8];
  }

  for (int t = 0; t < T_; ++t) {
    const int pc = t & 1, pr = pc ^ 1;

    // ---- phase W: h1 rendezvous + stage h1(t-1)@pr; waves2-3 poll f2
    if (t >= 1) waitflags(f1, t, 1);
    {
      u64 tmp[8];
      #pragma unroll
      for (int it = 0; it < 8; ++it) {
        int idx = tid + it*256; int b = idx >> 7, p = idx & 127;
        tmp[it] = ld_dc64(&h1bc[(size_t)pr*BH_ + (b0+b)*H_ + p*4]);
      }
      if (w >= 2 && t >= 2) {   // poll f2>=t-1 while h1 loads are in flight
        const int* p = f2 + lane;
        for (;;) {
          int v = __hip_atomic_load(p, __ATOMIC_RELAXED, __HIP_MEMORY_SCOPE_AGENT);
          if (__all(v >= t-1)) break;
          __builtin_amdgcn_s_sleep(1);
        }
      }
      #pragma unroll
      for (int it = 0; it < 8; ++it) {
        int idx = tid + it*256; int b = idx >> 7, p = idx & 127;
        *(u64*)&inA[b][256 + p*4] = tmp[it];
      }
    }
    __syncthreads();   // bar A

    // ---- phase A: L1 MFMA (waves 0-1) || stage h2(t-2)@pc (waves 2-3)
    if (w < 2) {
      const int nt = w;
      f32x4 a0 = (f32x4){0.f,0.f,0.f,0.f};
      f32x4 a1 = (f32x4){0.f,0.f,0.f,0.f};
      #pragma unroll
      for (int ks = 0; ks < 12; ++ks) {
        int k0 = ks*32 + q*8;
        a0 = __builtin_amdgcn_mfma_f32_16x16x32_bf16(
               *(const bf16x8*)&inA[n16][k0],
               *(const bf16x8*)&wl1[nt*16 + n16][k0], a0, 0,0,0);
        a1 = __builtin_amdgcn_mfma_f32_16x16x32_bf16(
               *(const bf16x8*)&inA[n16][384 + k0],
               *(const bf16x8*)&wl1[nt*16 + n16][384 + k0], a1, 0,0,0);
      }
      #pragma unroll
      for (int r = 0; r < 4; ++r) gbuf1[nt*16 + n16][q*4+r] = a0[r] + a1[r];
    } else if (t >= 1) {
      int tl = tid - 128;      // 0..127
      u64 tmp[16];
      #pragma unroll
      for (int it = 0; it < 16; ++it) {
        int idx = tl + it*128; int b = idx >> 7, p = idx & 127;
        tmp[it] = ld_dc64(&h2bc[(size_t)pc*BH_ + (b0+b)*H_ + p*4]);
      }
      #pragma unroll
      for (int it = 0; it < 16; ++it) {
        int idx = tl + it*128; int b = idx >> 7, p = idx & 127;
        *(u64*)&inA[b][768 + p*4] = tmp[it];
      }
    }
    __syncthreads();   // bar B

    // ---- phase B: EW1+publish (wave0) || L2 MFMA (waves1-2) || enc(t+1) (wave3)
    if (w == 0) {
      float hv[2];
      #pragma unroll
      for (int e = 0; e < 2; ++e) {
        int hc = 2*hp + e;
        float ip = gbuf1[hc][bE]      + b1r[0][e];
        float fp = gbuf1[8+hc][bE]    + b1r[1][e];
        float gp = gbuf1[16+hc][bE]   + b1r[2][e];
        float op = gbuf1[24+hc][bE]   + b1r[3][e];
        float c = sigf(fp)*cb1[e] + sigf(ip)*tanhfast(gp);
        cb1[e] = c;
        hv[e] = sigf(op)*tanhfast(c);
      }
      unsigned int pk = (unsigned int)f2bf(hv[0]) | ((unsigned int)f2bf(hv[1]) << 16);
      st_dc32(&h1bc[(size_t)pc*BH_ + (b0+bE)*H_ + hc0 + 2*hp], pk);
      if (t == T_-1) {
        *(float2*)&out_states[(size_t)0*BH_ + (b0+bE)*H_ + hc0 + 2*hp] = make_float2(hv[0], hv[1]);
        *(float2*)&out_states[(size_t)1*BH_ + (b0+bE)*H_ + hc0 + 2*hp] = make_float2(cb1[0], cb1[1]);
      }
      asm volatile("s_waitcnt vmcnt(0)" ::: "memory");
      if (tid == 0)
        __hip_atomic_store(&f1[j], t+1, __ATOMIC_RELAXED, __HIP_MEMORY_SCOPE_AGENT);
    } else if (w <= 2) {
      if (t >= 1) {
        const int nt = w - 1;
        f32x4 a0 = (f32x4){0.f,0.f,0.f,0.f};
        f32x4 a1 = (f32x4){0.f,0.f,0.f,0.f};
        #pragma unroll
        for (int ks = 0; ks < 16; ++ks) {
          int k0 = ks*32 + q*8;
          a0 = __builtin_amdgcn_mfma_f32_16x16x32_bf16(
                 *(const bf16x8*)&inA[n16][256 + k0],
                 *(const bf16x8*)&wl2[nt*16 + n16][k0], a0, 0,0,0);
          a1 = __builtin_amdgcn_mfma_f32_16x16x32_bf16(
                 *(const bf16x8*)&inA[n16][768 + k0],
                 *(const bf16x8*)&wl2[nt*16 + n16][512 + k0], a1, 0,0,0);
        }
        #pragma unroll
        for (int r = 0; r < 4; ++r) gbuf2[nt*16 + n16][q*4+r] = a0[r] + a1[r];
      }
    } else {
      if (t+1 < T_) {
        #pragma unroll
        for (int it = 0; it < 8; ++it) {
          int idx = lane + it*64;
          int b = idx >> 5, p = idx & 31;
          *(uint4*)&inA[b][p*8] =
            *(const uint4*)&enc_norm[((size_t)(b0+b)*T_ + (t+1))*E_ + p*8];
        }
      }
    }
    __syncthreads();   // bar C

    // ---- phase C: EW2 + publish h2(t-1)/x2 (wave0); others run to next W
    if (w == 0 && t >= 1) {
      float hv[2];
      #pragma unroll
      for (int e = 0; e < 2; ++e) {
        int hc = 2*hp + e;
        float ip = gbuf2[hc][bE]      + b2r[0][e];
        float fp = gbuf2[8+hc][bE]    + b2r[1][e];
        float gp = gbuf2[16+hc][bE]   + b2r[2][e];
        float op = gbuf2[24+hc][bE]   + b2r[3][e];
        float c = sigf(fp)*cb2[e] + sigf(ip)*tanhfast(gp);
        cb2[e] = c;
        hv[e] = sigf(op)*tanhfast(c);
      }
      unsigned int pk = (unsigned int)f2bf(hv[0]) | ((unsigned int)f2bf(hv[1]) << 16);
      st_dc32(&h2bc[(size_t)pr*BH_ + (b0+bE)*H_ + hc0 + 2*hp], pk);
      *(unsigned int*)&x2[((size_t)(b0+bE)*T_ + (t-1))*H_ + hc0 + 2*hp] = pk;
      asm volatile("s_waitcnt vmcnt(0)" ::: "memory");
      if (tid == 0)
        __hip_atomic_store(&f2[j], t, __ATOMIC_RELAXED, __HIP_MEMORY_SCOPE_AGENT);
    }
    // next iteration's waitflags barrier is the end-of-step sync
  }

  // ---- epilogue: h2(T-1) = f(h1(T-1), h2(T-2))
  {
    waitflags(f1, T_, 1);
    {  // h1(T-1) at parity 1
      u64 tmp[8];
      #pragma unroll
      for (int it = 0; it < 8; ++it) {
        int idx = tid + it*256; int b = idx >> 7, p = idx & 127;
        tmp[it] = ld_dc64(&h1bc[(size_t)1*BH_ + (b0+b)*H_ + p*4]);
      }
      #pragma unroll
      for (int it = 0; it < 8; ++it) {
        int idx = tid + it*256; int b = idx >> 7, p = idx & 127;
        *(u64*)&inA[b][256 + p*4] = tmp[it];
      }
    }
    waitflags(f2, T_-1, 2);   // also orders the h1 LDS writes above
    {  // h2(T-2) at parity 0
      u64 tmp[8];
      #pragma unroll
      for (int it = 0; it < 8; ++it) {
        int idx = tid + it*256; int b = idx >> 7, p = idx & 127;
        tmp[it] = ld_dc64(&h2bc[(size_t)0*BH_ + (b0+b)*H_ + p*4]);
      }
      #pragma unroll
      for (int it = 0; it < 8; ++it) {
        int idx = tid + it*256; int b = idx >> 7, p = idx & 127;
        *(u64*)&inA[b][768 + p*4] = tmp[it];
      }
    }
    __syncthreads();
    if (w == 1 || w == 2) {
      const int nt = w - 1;
      f32x4 a0 = (f32x4){0.f,0.f,0.f,0.f};
      f32x4 a1 = (f32x4){0.f,0.f,0.f,0.f};
      #pragma unroll
      for (int ks = 0; ks < 16; ++ks) {
        int k0 = ks*32 + q*8;
        a0 = __builtin_amdgcn_mfma_f32_16x16x32_bf16(
               *(const bf16x8*)&inA[n16][256 + k0],
               *(const bf16x8*)&wl2[nt*16 + n16][k0], a0, 0,0,0);
        a1 = __builtin_amdgcn_mfma_f32_16x16x32_bf16(
               *(const bf16x8*)&inA[n16][768 + k0],
               *(const bf16x8*)&wl2[nt*16 + n16][512 + k0], a1, 0,0,0);
      }
      #pragma unroll
      for (int r = 0; r < 4; ++r) gbuf2[nt*16 + n16][q*4+r] = a0[r] + a1[r];
    }
    __syncthreads();
    if (w == 0) {
      float hv[2];
      #pragma unroll
      for (int e = 0; e < 2; ++e) {
        int hc = 2*hp + e;
        float ip = gbuf2[hc][bE]      + b2r[0][e];
        float fp = gbuf2[8+hc][bE]    + b2r[1][e];
        float gp = gbuf2[16+hc][bE]   + b2r[2][e];
        float op = gbuf2[24+hc][bE]   + b2r[3][e];
        float c = sigf(fp)*cb2[e] + sigf(ip)*tanhfast(gp);
        cb2[e] = c;
        hv[e] = sigf(op)*tanhfast(c);
      }
      unsigned int pk = (unsigned int)f2bf(hv[0]) | ((unsigned int)f2bf(hv[1]) << 16);
      *(unsigned int*)&x2[((size_t)(b0+bE)*T_ + (T_-1))*H_ + hc0 + 2*hp] = pk;
      *(float2*)&out_states[(size_t)2*BH_ + (b0+bE)*H_ + hc0 + 2*hp] = make_float2(hv[0], hv[1]);
      *(float2*)&out_states[(size_t)3*BH_ + (b0+bE)*H_ + hc0 + 2*hp] = make_float2(cb2[0], cb2[1]);
    }
  }
}

// ---------------- mask GEMM + apply to encoded (in place -> est) ------------
__global__ __launch_bounds__(256) void k_mask(const unsigned short* __restrict__ x2,
    const unsigned short* __restrict__ wlinb, const float* __restrict__ blin,
    unsigned short* __restrict__ est) {
  const int bx = blockIdx.x;
  const int b = bx >> 6, tt = (bx & 63) << 4;
  const int tid = threadIdx.x, w = tid >> 6, lane = tid & 63;
  const int n16 = lane & 15, q = lane >> 4;
  f32x4 acc[4];
  #pragma unroll
  for (int i = 0; i < 4; ++i) acc[i] = (f32x4){0.f,0.f,0.f,0.f};
  const unsigned short* arow = x2 + ((size_t)b*1024 + tt)*512;
  for (int ks = 0; ks < 16; ++ks) {
    int k0 = ks*32 + q*8;
    bf16x8 af = *(const bf16x8*)&arow[(size_t)n16*512 + k0];
    #pragma unroll
    for (int i = 0; i < 4; ++i) {
      int o = (w*4+i)*16 + n16;
      bf16x8 bf = *(const bf16x8*)&wlinb[(size_t)o*512 + k0];
      acc[i] = __builtin_amdgcn_mfma_f32_16x16x32_bf16(af, bf, acc[i], 0,0,0);
    }
  }
  #pragma unroll
  for (int i = 0; i < 4; ++i) {
    int o = (w*4+i)*16 + n16;
    float bl = blin[o];
    #pragma unroll
    for (int r = 0; r < 4; ++r) {
      size_t p = ((size_t)b*1024 + tt + q*4 + r)*256 + o;
      float m = sigf(acc[i][r] + bl);
      est[p] = f2bf(m * bf2f(est[p]));
    }
  }
}

// ---------------- decoder GEMM: dec[b,f,t] = sum_o est[b,t,o] Wdec[f,o] -----
__global__ __launch_bounds__(256) void k_dec(const unsigned short* __restrict__ est,
    const unsigned short* __restrict__ wdecb, float* __restrict__ dec) {
  const int bx = blockIdx.x;                   // 64 * 8 * 16
  const int b = bx >> 7, rem = bx & 127, fy = rem >> 4, tx = rem & 15;
  const int f0 = fy*64, t0 = tx*64;
  const int tid = threadIdx.x, w = tid >> 6, lane = tid & 63;
  const int n16 = lane & 15, q = lane >> 4;
  f32x4 acc[4];
  #pragma unroll
  for (int i = 0; i < 4; ++i) acc[i] = (f32x4){0.f,0.f,0.f,0.f};
  const int fr = f0 + w*16 + n16;
  for (int ks = 0; ks < 8; ++ks) {
    int k0 = ks*32 + q*8;
    bf16x8 af = *(const bf16x8*)&wdecb[(size_t)fr*256 + k0];
    #pragma unroll
    for (int i = 0; i < 4; ++i) {
      int trow = t0 + i*16 + n16;
      bf16x8 bf = *(const bf16x8*)&est[((size_t)b*1024 + trow)*256 + k0];
      acc[i] = __builtin_amdgcn_mfma_f32_16x16x32_bf16(af, bf, acc[i], 0,0,0);
    }
  }
  #pragma unroll
  for (int i = 0; i < 4; ++i) {
    int tcol = t0 + i*16 + n16;
    #pragma unroll
    for (int r = 0; r < 4; ++r) {
      int f = f0 + w*16 + q*4 + r;
      dec[((size_t)b*512 + f)*1024 + tcol] = acc[i][r];
    }
  }
}

extern "C" void kernel_launch(void* const* d_in, const int* in_sizes, int n_in,
                              void* d_out, int out_size, void* d_ws, size_t ws_size,
                              hipStream_t stream) {
  (void)in_sizes; (void)n_in; (void)out_size; (void)ws_size;
  const float* x      = (const float*)d_in[0];
  const float* states = (const float*)d_in[1];
  const float* Wenc   = (const float*)d_in[2];
  const float* lng    = (const float*)d_in[3];
  const float* lnb    = (const float*)d_in[4];
  const float* Wih1   = (const float*)d_in[5];
  const float* Whh1   = (const float*)d_in[6];
  const float* bih1   = (const float*)d_in[7];
  const float* bhh1   = (const float*)d_in[8];
  const float* Wih2   = (const float*)d_in[9];
  const float* Whh2   = (const float*)d_in[10];
  const float* bih2   = (const float*)d_in[11];
  const float* bhh2   = (const float*)d_in[12];
  const float* Wlin   = (const float*)d_in[13];
  const float* blin   = (const float*)d_in[14];
  const float* Wdec   = (const float*)d_in[15];

  float* dec = (float*)d_out;
  float* out_states = dec + DEC_ELEMS;

  char* ws = (char*)d_ws;
  unsigned short* enc_norm = (unsigned short*)ws; ws += (size_t)B_*T_*E_*2;   // 32 MB
  unsigned short* encoded  = (unsigned short*)ws; ws += (size_t)B_*T_*E_*2;   // 32 MB (est in place)
  unsigned short* x2buf    = (unsigned short*)ws; ws += (size_t)B_*T_*H_*2;   // 64 MB
  unsigned short* wencb    = (unsigned short*)ws; ws += 131072*2;
  unsigned short* wlinb    = (unsigned short*)ws; ws += 131072*2;
  unsigned short* wdecb    = (unsigned short*)ws; ws += 131072*2;
  unsigned short* h1bc     = (unsigned short*)ws; ws += 2*BH_*2;
  unsigned short* h2bc     = (unsigned short*)ws; ws += 2*BH_*2;
  int* flags               = (int*)ws;            ws += 2*4*64*4;

  (void)hipMemsetAsync(flags, 0, 2*4*64*4, stream);
  k_prep<<<512, 256, 0, stream>>>(Wenc, Wlin, Wdec, states, wencb, wlinb, wdecb, h1bc, h2bc);
  k_enc<<<4096, 256, 0, stream>>>(x, wencb, lng, lnb, enc_norm, encoded);
  k_recur<<<256, 256, 0, stream>>>(states, Wih1, Whh1, bih1, bhh1,
                                   Wih2, Whh2, bih2, bhh2,
                                   enc_norm, x2buf, h1bc, h2bc,
                                   flags, flags + 4*64, out_states);
  k_mask<<<4096, 256, 0, stream>>>(x2buf, wlinb, blin, encoded);
  k_dec<<<8192, 256, 0, stream>>>(encoded, wdecb, dec);
}